// Round 1
// baseline (7501.608 us; speedup 1.0000x reference)
//
#include <hip/hip_runtime.h>

// TriPlanePC2Encoder: scatter-mean of point features onto 3 canonical planes.
// B=8, N=200000, C=32, R=128. out[b, plane, c, row, col], plane order xy,yz,xz.
// Baseline: global-atomic scatter (sums into d_out, counts into d_ws), then
// normalize. Binning replicates the fp32 IEEE op order of the JAX reference
// exactly: v=(p+1)*0.5-0.5 ; t=v/1.00001f+0.5 ; clip[0, 1-1e-5] ; (int)(t*128).

constexpr int R     = 128;
constexpr int NBINS = R * R;        // 16384 = 2^14
constexpr int NPTS  = 200000;
constexpr int NB    = 8;
constexpr int NC    = 32;           // 2^5

__device__ __forceinline__ int coord_bin(float p) {
    // xyz_norm = (p - (-1)) / 2 - 0.5  -- division by 2 is exact halving
    float v = (p + 1.0f) * 0.5f - 0.5f;
    // normalize_coordinate: /(1+0+eps) + 0.5, clip, *R, int-trunc
    float t = v / 1.00001f + 0.5f;            // IEEE fp32 divide (no fast-math)
    t = fminf(fmaxf(t, 0.0f), (float)(1.0 - 1e-5));
    return (int)(t * 128.0f);
}

__global__ __launch_bounds__(256) void scatter_kernel(
    const float* __restrict__ xyz, const float* __restrict__ feat,
    float* __restrict__ out, int* __restrict__ cnt) {
    int i = blockIdx.x * 256 + threadIdx.x;
    if (i >= NB * NPTS) return;
    int b = i / NPTS;
    int n = i - b * NPTS;

    float x = xyz[3 * (size_t)i + 0];
    float y = xyz[3 * (size_t)i + 1];
    float z = xyz[3 * (size_t)i + 2];
    int ix = coord_bin(x);
    int iy = coord_bin(y);
    int iz = coord_bin(z);
    // plane dims: xy=(0,1) yz=(1,2) xz=(0,2); lin = idx_d0 + R*idx_d1
    int bxy = ix + R * iy;
    int byz = iy + R * iz;
    int bxz = ix + R * iz;

    int* cb = cnt + (size_t)b * 3 * NBINS;
    atomicAdd(cb + 0 * NBINS + bxy, 1);
    atomicAdd(cb + 1 * NBINS + byz, 1);
    atomicAdd(cb + 2 * NBINS + bxz, 1);

    const float* f = feat + (size_t)b * NC * NPTS + n;
    float* ob = out + (size_t)b * 3 * NC * NBINS;
#pragma unroll 4
    for (int c = 0; c < NC; ++c) {
        float fv = f[(size_t)c * NPTS];          // coalesced across lanes
        atomicAdd(ob + (size_t)(0 * NC + c) * NBINS + bxy, fv);
        atomicAdd(ob + (size_t)(1 * NC + c) * NBINS + byz, fv);
        atomicAdd(ob + (size_t)(2 * NC + c) * NBINS + bxz, fv);
    }
}

__global__ __launch_bounds__(256) void normalize_kernel(
    float* __restrict__ out, const int* __restrict__ cnt) {
    int i = blockIdx.x * 256 + threadIdx.x;
    if (i >= NB * 3 * NC * NBINS) return;
    int bin  = i & (NBINS - 1);
    int bp   = i >> (14 + 5);                    // (b*3 + plane)
    float cf = (float)cnt[(size_t)bp * NBINS + bin];
    out[i] = out[i] / fmaxf(cf, 1.0f);           // empty bins: 0/1 = 0
}

extern "C" void kernel_launch(void* const* d_in, const int* in_sizes, int n_in,
                              void* d_out, int out_size, void* d_ws, size_t ws_size,
                              hipStream_t stream) {
    const float* xyz  = (const float*)d_in[0];   // (B, N, 3)
    const float* feat = (const float*)d_in[1];   // (B, C, N)
    float* out = (float*)d_out;                  // (B, 3, C, R, R)
    int*   cnt = (int*)d_ws;                     // (B, 3, NBINS)

    hipMemsetAsync(d_out, 0, (size_t)out_size * sizeof(float), stream);
    hipMemsetAsync(d_ws, 0, (size_t)NB * 3 * NBINS * sizeof(int), stream);

    int total_pts = NB * NPTS;
    scatter_kernel<<<(total_pts + 255) / 256, 256, 0, stream>>>(xyz, feat, out, cnt);

    int total_out = NB * 3 * NC * NBINS;
    normalize_kernel<<<(total_out + 255) / 256, 256, 0, stream>>>(out, cnt);
}

// Round 2
// 1009.475 us; speedup vs baseline: 7.4312x; 7.4312x over previous
//
#include <hip/hip_runtime.h>

// TriPlanePC2Encoder: scatter-mean of point features onto 3 canonical planes.
// B=8, N=200000, C=32, R=128. out[b, plane, c, row, col], plane order xy,yz,xz.
//
// Round 2: LDS-privatized histograms, zero global atomics on the fp32 sums.
//   1. bin_kernel:    per point, compute 3 plane bin ids once -> u16 arrays in ws.
//   2. count_kernel:  LDS u32 histogram per (b,plane,split), atomic flush.
//   3. scatter_kernel: one block per (b,plane,ch); 64 KB LDS fp32 histogram;
//      exclusive output ownership -> plain-store flush fused with the
//      count-divide (no separate normalize kernel, no d_out memset).

constexpr int R     = 128;
constexpr int NBINS = R * R;        // 16384
constexpr int NPTS  = 200000;
constexpr int NB    = 8;
constexpr int NC    = 32;
constexpr int SPLIT = 4;            // point-splits in count_kernel

// ws layout: bins u16 [3][NB][NPTS]  (9,600,000 B), then cnt u32 [NB][3][NBINS]
constexpr size_t BINS_BYTES = (size_t)3 * NB * NPTS * sizeof(unsigned short);
constexpr size_t CNT_WORDS  = (size_t)NB * 3 * NBINS;

__device__ __forceinline__ int coord_bin(float p) {
    // xyz_norm = (p+1)/2 - 0.5 ; then /(1+eps) + 0.5 ; clip ; *R ; trunc
    float v = (p + 1.0f) * 0.5f - 0.5f;
    float t = v / 1.00001f + 0.5f;                     // IEEE fp32 divide
    t = fminf(fmaxf(t, 0.0f), (float)(1.0 - 1e-5));
    return (int)(t * 128.0f);
}

__global__ __launch_bounds__(256) void bin_kernel(
    const float* __restrict__ xyz, unsigned short* __restrict__ bins) {
    int i = blockIdx.x * 256 + threadIdx.x;            // over B*N
    if (i >= NB * NPTS) return;
    float x = xyz[3 * (size_t)i + 0];
    float y = xyz[3 * (size_t)i + 1];
    float z = xyz[3 * (size_t)i + 2];
    int ix = coord_bin(x), iy = coord_bin(y), iz = coord_bin(z);
    // plane dims: xy=(0,1) yz=(1,2) xz=(0,2); lin = idx_d0 + R*idx_d1
    bins[0 * (size_t)NB * NPTS + i] = (unsigned short)(ix + R * iy);
    bins[1 * (size_t)NB * NPTS + i] = (unsigned short)(iy + R * iz);
    bins[2 * (size_t)NB * NPTS + i] = (unsigned short)(ix + R * iz);
}

__global__ __launch_bounds__(1024) void count_kernel(
    const unsigned short* __restrict__ bins, unsigned* __restrict__ cnt) {
    __shared__ unsigned hist[NBINS];
    int blk   = blockIdx.x;                 // (b*3+plane)*SPLIT + split
    int split = blk & (SPLIT - 1);
    int bp    = blk >> 2;                   // b*3 + plane
    int b     = bp / 3;
    int plane = bp - 3 * b;
    for (int i = threadIdx.x; i < NBINS; i += 1024) hist[i] = 0u;
    __syncthreads();
    const unsigned short* src = bins + ((size_t)plane * NB + b) * NPTS
                                     + (size_t)split * (NPTS / SPLIT);
    for (int n = threadIdx.x; n < NPTS / SPLIT; n += 1024)
        atomicAdd(&hist[src[n]], 1u);
    __syncthreads();
    unsigned* dst = cnt + (size_t)bp * NBINS;
    for (int i = threadIdx.x; i < NBINS; i += 1024) {
        unsigned v = hist[i];
        if (v) atomicAdd(&dst[i], v);
    }
}

__global__ __launch_bounds__(1024) void scatter_kernel(
    const unsigned short* __restrict__ bins, const float* __restrict__ feat,
    const unsigned* __restrict__ cnt, float* __restrict__ out) {
    __shared__ float hist[NBINS];           // 64 KB -> 2 blocks/CU
    int blk   = blockIdx.x;                 // b*96 + plane*32 + ch
    int b     = blk / 96;
    int rem   = blk - b * 96;
    int plane = rem >> 5;
    int ch    = rem & 31;
    for (int i = threadIdx.x; i < NBINS; i += 1024) hist[i] = 0.0f;
    __syncthreads();
    // process 2 points per thread (u16x2 + float2 loads); NPTS is even
    const unsigned* bp2 = (const unsigned*)(bins + ((size_t)plane * NB + b) * NPTS);
    const float2*   fp2 = (const float2*)(feat + ((size_t)b * NC + ch) * NPTS);
    for (int p = threadIdx.x; p < NPTS / 2; p += 1024) {
        unsigned bb = bp2[p];
        float2   ff = fp2[p];
        atomicAdd(&hist[bb & 0xffffu], ff.x);
        atomicAdd(&hist[bb >> 16], ff.y);
    }
    __syncthreads();
    const unsigned* cb = cnt + ((size_t)b * 3 + plane) * NBINS;
    float* ob = out + (((size_t)b * 3 + plane) * NC + ch) * (size_t)NBINS;
    for (int i = threadIdx.x; i < NBINS; i += 1024)
        ob[i] = hist[i] / fmaxf((float)cb[i], 1.0f);   // empty bins: 0/1 = 0
}

extern "C" void kernel_launch(void* const* d_in, const int* in_sizes, int n_in,
                              void* d_out, int out_size, void* d_ws, size_t ws_size,
                              hipStream_t stream) {
    const float* xyz  = (const float*)d_in[0];         // (B, N, 3)
    const float* feat = (const float*)d_in[1];         // (B, C, N)
    float* out = (float*)d_out;                        // (B, 3, C, R, R)
    unsigned short* bins = (unsigned short*)d_ws;
    unsigned* cnt = (unsigned*)((char*)d_ws + BINS_BYTES);

    hipMemsetAsync(cnt, 0, CNT_WORDS * sizeof(unsigned), stream);

    int total_pts = NB * NPTS;
    bin_kernel<<<(total_pts + 255) / 256, 256, 0, stream>>>(xyz, bins);
    count_kernel<<<NB * 3 * SPLIT, 1024, 0, stream>>>(bins, cnt);
    scatter_kernel<<<NB * 3 * NC, 1024, 0, stream>>>(bins, feat, cnt, out);
}